// Round 8
// baseline (47.453 us; speedup 1.0000x reference)
//
#include <hip/hip_runtime.h>
#include <math.h>

// HarmonicGenerator, 2 kernels, NO memset (init-free finisher election).
// K1 hg_prep: 128 blocks = (n, cg). Phase 1: per-frame partial sums over 32
//   channels (coalesced, f64 norm/octave chains). Election: atomicOr of
//   (1<<cg) into cnt[n]; a block finishes iff low byte becomes full (the
//   LAST arriver always does, regardless of cnt's initial garbage; extra
//   finishers write byte-identical params -> benign). Finisher: combine ->
//   stats -> f0 (f64) -> prefix scan -> per-region f32 params
//   {frac(P'), S', Q, 0.125*magA[8], 0.125*magD[8]}, then clears the byte.
// K2 hg_wave: 4 tiles/block; pure f32; per sample one v_fract+v_sin+v_cos,
//   harmonics 2..8 via Chebyshev recurrence; float4 stores.
// N=16, C=256, LF=200, SEG=960, Lw=192000, NH=8, SR=48000.

#define NB   16
#define CCH  256
#define LFR  200
#define LW   192000
#define NHH  8
#define NKM  201
#define NT   (NB * NKM)     // 3216 tiles
#define CG   8              // producer blocks per n
#define CPB  32             // channels per producer block
#define INV_SR (1.0 / 48000.0)
#define PSTRIDE 20          // floats per (n,km) param record
#define TPB  4              // tiles per wave-kernel block

__device__ inline double wave_sum64(double v) {
    #pragma unroll
    for (int off = 32; off > 0; off >>= 1) v += __shfl_xor(v, off);
    return v;
}
__device__ inline double wave_incl_scan64(double v) {
    int lane = threadIdx.x & 63;
    #pragma unroll
    for (int off = 1; off < 64; off <<= 1) {
        double t = __shfl_up(v, off);
        if (lane >= off) v += t;
    }
    return v;
}

__global__ __launch_bounds__(256)
void hg_prep(const float* __restrict__ x,
             const float* __restrict__ mag_w, const float* __restrict__ mag_b,
             const float* __restrict__ cn_scale, const float* __restrict__ cn_shift,
             const float* __restrict__ oct_w, const float* __restrict__ oct_b,
             unsigned int* __restrict__ cnt,   // cnt[n*32], 128B-padded, NO init
             double* __restrict__ ps, double* __restrict__ ps2,
             double* __restrict__ pdx, float* __restrict__ pmg,
             float* __restrict__ params) {
    __shared__ double Fl[LFR];
    __shared__ double Tl[LFR];
    __shared__ float  Mgl[LFR][NHH];
    __shared__ double SAB[2];
    __shared__ int    is_fin;

    int b = blockIdx.x;
    int tid = threadIdx.x;
    int n = b >> 3, cg = b & 7;

    // ---------------- Phase 1: partial sums ----------------
    const float* xb = x + (size_t)n * CCH * LFR;
    int cbase = cg * CPB;

    double s = 0.0, s2 = 0.0, dx = 0.0;
    float zm[NHH] = {0.f, 0.f, 0.f, 0.f, 0.f, 0.f, 0.f, 0.f};
    #pragma unroll 8
    for (int cc = 0; cc < CPB; cc++) {
        int c = cbase + cc;
        float xf = (tid < LFR) ? xb[(size_t)c * LFR + tid] : 0.f;
        double xd = (double)xf;
        double w2 = (double)cn_scale[c] * (double)oct_w[c];
        s += xd;
        s2 = fma(xd, xd, s2);
        dx = fma(xd, w2, dx);
        #pragma unroll
        for (int h = 0; h < NHH; h++)
            zm[h] = fmaf(xf, mag_w[h * CCH + c], zm[h]);
    }
    size_t pi = ((size_t)n * CG + cg) * 256 + tid;
    ps[pi] = s; ps2[pi] = s2; pdx[pi] = dx;
    #pragma unroll
    for (int h = 0; h < NHH; h++)
        pmg[(((size_t)n * CG + cg) * NHH + h) * 256 + tid] = zm[h];

    __threadfence();
    __syncthreads();
    if (tid == 0) {
        unsigned int mybit = 1u << cg;
        unsigned int old = __hip_atomic_fetch_or(&cnt[n * 32], mybit,
                              __ATOMIC_ACQ_REL, __HIP_MEMORY_SCOPE_AGENT);
        is_fin = (((old | mybit) & 0xFFu) == 0xFFu);
    }
    __syncthreads();
    if (!is_fin) return;

    // ---------------- Phase 2: finisher builds tables for n ----------------
    __threadfence();
    // SA = sum(scale*ow), SB = sum(shift*ow)  (wave 0, f64)
    if (tid < 64) {
        double sa = 0.0, sb = 0.0;
        #pragma unroll
        for (int k = 0; k < 4; k++) {
            int c = tid + 64 * k;
            double ow = (double)oct_w[c];
            sa = fma((double)cn_scale[c], ow, sa);
            sb = fma((double)cn_shift[c], ow, sb);
        }
        sa = wave_sum64(sa);
        sb = wave_sum64(sb);
        if (tid == 0) { SAB[0] = sa; SAB[1] = sb; }
    }
    __syncthreads();

    if (tid < LFR) {
        double s_ = 0.0, s2_ = 0.0, dx_ = 0.0;
        #pragma unroll
        for (int cg2 = 0; cg2 < CG; cg2++) {
            size_t pj = ((size_t)n * CG + cg2) * 256 + tid;
            s_ += ps[pj]; s2_ += ps2[pj]; dx_ += pdx[pj];
        }
        double mu  = s_ * (1.0 / 256.0);
        double var = (s2_ - s_ * mu) * (1.0 / 255.0);
        double inv = 1.0 / (sqrt(var) + 1e-4);          // unbiased std + EPS
        double oct = inv * (dx_ - mu * SAB[0]) + SAB[1] + (double)oct_b[0];
        double f0  = 440.0 * exp2(oct);
        Fl[tid] = fmin(fmax(f0, 20.0), 16000.0);
        #pragma unroll
        for (int h = 0; h < NHH; h++) {
            float z = 0.f;
            #pragma unroll
            for (int cg2 = 0; cg2 < CG; cg2++)
                z += pmg[(((size_t)n * CG + cg2) * NHH + h) * 256 + tid];
            Mgl[tid][h] = expf(fminf(z + mag_b[h], 6.f));
        }
    }
    __syncthreads();

    // exclusive scan: Tl[k] = 480*F[0] + sum_{i<k} 480*(F[i]+F[i+1])
    if (tid < 64) {
        double carry = 480.0 * Fl[0];
        for (int base = 0; base < LFR; base += 64) {
            int k = base + tid;
            double d = (k < LFR - 1) ? 480.0 * (Fl[k] + Fl[k + 1]) : 0.0;
            double scn = wave_incl_scan64(d);
            if (k < LFR) Tl[k] = carry + scn - d;
            carry += __shfl(scn, 63);
        }
    }
    __syncthreads();

    // params, recentered: tb(pc) = P' + S'*pc + Q*pc^2, pc in [-479,480]
    if (tid < NKM) {
        int km = tid;
        int kc = min(max(km - 1, 0), LFR - 1);
        bool body = (km >= 1 && km <= LFR - 1);
        double Sd = Fl[kc] * INV_SR;
        double Qd = body ? (Fl[km] - Fl[km - 1]) * (INV_SR / 1920.0) : 0.0;
        double Pd = (km == 0) ? (-480.0 * Fl[0] * INV_SR) : Tl[km - 1] * INV_SR;
        double Pp = Pd + 480.0 * Sd + 230400.0 * Qd;
        double Sp = Sd + 960.0 * Qd;
        float* pr = params + ((size_t)n * NKM + km) * PSTRIDE;
        pr[0] = (float)(Pp - floor(Pp));
        pr[1] = (float)Sp;
        pr[2] = (float)Qd;
        pr[3] = 0.f;
        #pragma unroll
        for (int h = 0; h < NHH; h++) {
            float a = Mgl[kc][h];
            pr[4 + h]  = 0.125f * a;                         // fold mean
            pr[12 + h] = body ? 0.125f * (Mgl[km][h] - a) : 0.f;
        }
    }
    __syncthreads();
    // reset election byte so every later replay starts from 0 (idempotent)
    if (tid == 0)
        __hip_atomic_fetch_and(&cnt[n * 32], ~0xFFu,
                               __ATOMIC_RELEASE, __HIP_MEMORY_SCOPE_AGENT);
}

// K2: 4 tiles (km,n) per block; 4 consecutive samples/thread per tile.
// Chebyshev: s_{h+1} = 2*cos(2*pi*f)*s_h - s_{h-1}.
__global__ __launch_bounds__(256)
void hg_wave(const float* __restrict__ params, float* __restrict__ out) {
    int tid = threadIdx.x;
    #pragma unroll
    for (int i = 0; i < TPB; i++) {
        int tile = blockIdx.x * TPB + i;               // 0..3215
        int n = tile / NKM, km = tile - n * NKM;
        const float4* pb = (const float4*)(params + (size_t)tile * PSTRIDE);
        float4 v0 = pb[0], v1 = pb[1], v2 = pb[2], v3 = pb[3], v4 = pb[4];
        float Pf = v0.x, Sf = v0.y, Qf = v0.z;
        float ma[NHH] = {v1.x, v1.y, v1.z, v1.w, v2.x, v2.y, v2.z, v2.w};
        float md[NHH] = {v3.x, v3.y, v3.z, v3.w, v4.x, v4.y, v4.z, v4.w};

        if (tid >= 240) continue;
        int j0 = 960 * km - 480 + tid * 4;
        if (j0 < 0 || j0 >= LW) continue;              // clipped head/tail

        float r[4];
        #pragma unroll
        for (int u = 0; u < 4; u++) {
            float pc = (float)(tid * 4 - 479 + u);     // [-479, 480]
            float tb = fmaf(pc, fmaf(Qf, pc, Sf), Pf); // phase (cycles)
            float fr, s1, c1;
            asm("v_fract_f32 %0, %1" : "=v"(fr) : "v"(tb));
            asm("v_sin_f32 %0, %1" : "=v"(s1) : "v"(fr));
            asm("v_cos_f32 %0, %1" : "=v"(c1) : "v"(fr));
            float twoc = c1 + c1;
            float w = (pc + 479.5f) * (1.0f / 960.0f);
            float sp = 0.f, sc = s1;                   // s_0, s_1
            float acc = 0.f;
            #pragma unroll
            for (int h = 0; h < NHH; h++) {
                acc = fmaf(fmaf(md[h], w, ma[h]), sc, acc);
                float sn = fmaf(twoc, sc, -sp);
                sp = sc; sc = sn;
            }
            r[u] = acc;
        }
        *(float4*)(out + (size_t)n * LW + j0) = make_float4(r[0], r[1], r[2], r[3]);
    }
}

extern "C" void kernel_launch(void* const* d_in, const int* in_sizes, int n_in,
                              void* d_out, int out_size, void* d_ws, size_t ws_size,
                              hipStream_t stream) {
    const float* x        = (const float*)d_in[0];
    const float* mag_w    = (const float*)d_in[1];
    const float* mag_b    = (const float*)d_in[2];
    const float* cn_scale = (const float*)d_in[3];
    const float* cn_shift = (const float*)d_in[4];
    const float* oct_w    = (const float*)d_in[5];
    const float* oct_b    = (const float*)d_in[6];
    float* out = (float*)d_out;

    // ws: cnt uint[16*32] (2KB) | ps|ps2|pdx f64[NB*CG*256] | pmg f32 | params f32
    unsigned int* cnt = (unsigned int*)d_ws;
    double* ps  = (double*)((char*)d_ws + 2048);
    double* ps2 = ps  + (size_t)NB * CG * 256;
    double* pdx = ps2 + (size_t)NB * CG * 256;
    float*  pmg = (float*)(pdx + (size_t)NB * CG * 256);
    float*  params = pmg + (size_t)NB * CG * NHH * 256;

    hg_prep<<<dim3(NB * CG), dim3(256), 0, stream>>>(
        x, mag_w, mag_b, cn_scale, cn_shift, oct_w, oct_b,
        cnt, ps, ps2, pdx, pmg, params);
    hg_wave<<<dim3(NT / TPB), dim3(256), 0, stream>>>(params, out);
}

// Round 9
// 24.493 us; speedup vs baseline: 1.9375x; 1.9375x over previous
//
#include <hip/hip_runtime.h>
#include <math.h>

// HarmonicGenerator, 2 kernels, NO atomics / NO memset / no cross-block sync.
// K1 hg_partial: 128 blocks = (n,cg); per-frame partial sums over 32 channels
//   (coalesced loads; f64 chains for norm/octave, f32 for mag dots).
// K2 hg_wave: grid (51 km-groups, 16 n). Each block REDUNDANTLY rebuilds the
//   per-n tables from the partials (L2-hot, ~90 KB/n shared by 51 blocks):
//   combine -> stats -> f0 (f64) -> 200-elem prefix scan (wave 0) -> then
//   evaluates 4 regions: recentered phase polynomial in f64 once per tile,
//   per-sample pure-f32 with one v_fract+v_sin+v_cos and Chebyshev
//   recurrence for harmonics 2..8; float4 stores.
// N=16, C=256, LF=200, SEG=960, Lw=192000, NH=8, SR=48000.

#define NB   16
#define CCH  256
#define LFR  200
#define LW   192000
#define NHH  8
#define NKM  201
#define CG   8       // channel groups (blocks) per n
#define CPB  32      // channels per group
#define INV_SR (1.0 / 48000.0)
#define TPB  4       // regions per wave-kernel block
#define KMB  ((NKM + TPB - 1) / TPB)   // 51

__device__ inline double wave_sum64(double v) {
    #pragma unroll
    for (int off = 32; off > 0; off >>= 1) v += __shfl_xor(v, off);
    return v;
}
__device__ inline double wave_incl_scan64(double v) {
    int lane = threadIdx.x & 63;
    #pragma unroll
    for (int off = 1; off < 64; off <<= 1) {
        double t = __shfl_up(v, off);
        if (lane >= off) v += t;
    }
    return v;
}

// K1: partial sums. Thread = frame slot t; loops CPB channels (uniform c ->
// scalar weight loads, coalesced x loads across t).
__global__ __launch_bounds__(256)
void hg_partial(const float* __restrict__ x,
                const float* __restrict__ mag_w,
                const float* __restrict__ cn_scale,
                const float* __restrict__ oct_w,
                double* __restrict__ ps, double* __restrict__ ps2,
                double* __restrict__ pdx, float* __restrict__ pmg) {
    int n = blockIdx.x, cg = blockIdx.y;
    int t = threadIdx.x;
    const float* xb = x + (size_t)n * CCH * LFR;
    int cbase = cg * CPB;

    double s = 0.0, s2 = 0.0, dx = 0.0;
    float zm[NHH] = {0.f, 0.f, 0.f, 0.f, 0.f, 0.f, 0.f, 0.f};
    #pragma unroll 8
    for (int cc = 0; cc < CPB; cc++) {
        int c = cbase + cc;
        float xf = (t < LFR) ? xb[(size_t)c * LFR + t] : 0.f;
        double xd = (double)xf;
        double w2 = (double)cn_scale[c] * (double)oct_w[c];
        s += xd;
        s2 = fma(xd, xd, s2);
        dx = fma(xd, w2, dx);
        #pragma unroll
        for (int h = 0; h < NHH; h++)
            zm[h] = fmaf(xf, mag_w[h * CCH + c], zm[h]);
    }
    size_t pi = ((size_t)n * CG + cg) * 256 + t;
    ps[pi] = s; ps2[pi] = s2; pdx[pi] = dx;
    #pragma unroll
    for (int h = 0; h < NHH; h++)
        pmg[(((size_t)n * CG + cg) * NHH + h) * 256 + t] = zm[h];
}

// K2: tables (redundant per block, L2-hot) + wave evaluation.
__global__ __launch_bounds__(256)
void hg_wave(const double* __restrict__ ps, const double* __restrict__ ps2,
             const double* __restrict__ pdx, const float* __restrict__ pmg,
             const float* __restrict__ mag_b,
             const float* __restrict__ cn_scale, const float* __restrict__ cn_shift,
             const float* __restrict__ oct_w, const float* __restrict__ oct_b,
             float* __restrict__ out) {
    __shared__ double Fl[LFR];
    __shared__ double Tl[LFR];
    __shared__ float  Mgl[LFR][NHH];
    __shared__ double SAB[2];

    int n = blockIdx.y;
    int tid = threadIdx.x;

    // SA = sum(scale*ow), SB = sum(shift*ow)  (wave 0, f64; inputs L2-hot)
    if (tid < 64) {
        double sa = 0.0, sb = 0.0;
        #pragma unroll
        for (int k = 0; k < 4; k++) {
            int c = tid + 64 * k;
            double ow = (double)oct_w[c];
            sa = fma((double)cn_scale[c], ow, sa);
            sb = fma((double)cn_shift[c], ow, sb);
        }
        sa = wave_sum64(sa);
        sb = wave_sum64(sb);
        if (tid == 0) { SAB[0] = sa; SAB[1] = sb; }
    }
    __syncthreads();

    // combine partials + per-frame stats (thread = frame)
    if (tid < LFR) {
        double s_ = 0.0, s2_ = 0.0, dx_ = 0.0;
        #pragma unroll
        for (int cg2 = 0; cg2 < CG; cg2++) {
            size_t pj = ((size_t)n * CG + cg2) * 256 + tid;
            s_ += ps[pj]; s2_ += ps2[pj]; dx_ += pdx[pj];
        }
        double mu  = s_ * (1.0 / 256.0);
        double var = (s2_ - s_ * mu) * (1.0 / 255.0);
        double inv = 1.0 / (sqrt(var) + 1e-4);          // unbiased std + EPS
        double oct = inv * (dx_ - mu * SAB[0]) + SAB[1] + (double)oct_b[0];
        double f0  = 440.0 * exp2(oct);
        Fl[tid] = fmin(fmax(f0, 20.0), 16000.0);
        #pragma unroll
        for (int h = 0; h < NHH; h++) {
            float z = 0.f;
            #pragma unroll
            for (int cg2 = 0; cg2 < CG; cg2++)
                z += pmg[(((size_t)n * CG + cg2) * NHH + h) * 256 + tid];
            Mgl[tid][h] = 0.125f * expf(fminf(z + mag_b[h], 6.f));  // fold mean
        }
    }
    __syncthreads();

    // exclusive scan: Tl[k] = 480*F[0] + sum_{i<k} 480*(F[i]+F[i+1])  (wave 0)
    if (tid < 64) {
        double carry = 480.0 * Fl[0];
        for (int base = 0; base < LFR; base += 64) {
            int k = base + tid;
            double d = (k < LFR - 1) ? 480.0 * (Fl[k] + Fl[k + 1]) : 0.0;
            double scn = wave_incl_scan64(d);
            if (k < LFR) Tl[k] = carry + scn - d;
            carry += __shfl(scn, 63);
        }
    }
    __syncthreads();

    // evaluate TPB regions; recentered: tb(pc) = P' + S'*pc + Q*pc^2
    #pragma unroll
    for (int i = 0; i < TPB; i++) {
        int km = blockIdx.x * TPB + i;
        if (km >= NKM) break;
        int kc = min(max(km - 1, 0), LFR - 1);
        bool body = (km >= 1 && km <= LFR - 1);
        double Sd = Fl[kc] * INV_SR;
        double Qd = body ? (Fl[km] - Fl[km - 1]) * (INV_SR / 1920.0) : 0.0;
        double Pd = (km == 0) ? (-480.0 * Fl[0] * INV_SR) : Tl[km - 1] * INV_SR;
        double Pp = Pd + 480.0 * Sd + 230400.0 * Qd;
        double Sp = Sd + 960.0 * Qd;
        float Pf = (float)(Pp - floor(Pp));
        float Sf = (float)Sp;
        float Qf = (float)Qd;
        float ma[NHH], md[NHH];
        #pragma unroll
        for (int h = 0; h < NHH; h++) {
            float a = Mgl[kc][h];
            ma[h] = a;
            md[h] = body ? (Mgl[km][h] - a) : 0.f;
        }

        if (tid < 240) {
            int j0 = 960 * km - 480 + tid * 4;
            if (j0 >= 0 && j0 < LW) {
                float r[4];
                #pragma unroll
                for (int u = 0; u < 4; u++) {
                    float pc = (float)(tid * 4 - 479 + u);     // [-479, 480]
                    float tb = fmaf(pc, fmaf(Qf, pc, Sf), Pf); // phase (cycles)
                    float fr, s1, c1;
                    asm("v_fract_f32 %0, %1" : "=v"(fr) : "v"(tb));
                    asm("v_sin_f32 %0, %1" : "=v"(s1) : "v"(fr));
                    asm("v_cos_f32 %0, %1" : "=v"(c1) : "v"(fr));
                    float twoc = c1 + c1;
                    float w = (pc + 479.5f) * (1.0f / 960.0f);
                    float sp = 0.f, sc = s1;                   // Chebyshev
                    float acc = 0.f;
                    #pragma unroll
                    for (int h = 0; h < NHH; h++) {
                        acc = fmaf(fmaf(md[h], w, ma[h]), sc, acc);
                        float sn = fmaf(twoc, sc, -sp);
                        sp = sc; sc = sn;
                    }
                    r[u] = acc;
                }
                *(float4*)(out + (size_t)n * LW + j0) =
                    make_float4(r[0], r[1], r[2], r[3]);
            }
        }
    }
}

extern "C" void kernel_launch(void* const* d_in, const int* in_sizes, int n_in,
                              void* d_out, int out_size, void* d_ws, size_t ws_size,
                              hipStream_t stream) {
    const float* x        = (const float*)d_in[0];
    const float* mag_w    = (const float*)d_in[1];
    const float* mag_b    = (const float*)d_in[2];
    const float* cn_scale = (const float*)d_in[3];
    const float* cn_shift = (const float*)d_in[4];
    const float* oct_w    = (const float*)d_in[5];
    const float* oct_b    = (const float*)d_in[6];
    float* out = (float*)d_out;

    // ws: ps|ps2|pdx f64[NB*CG*256] each | pmg f32[NB*CG*8*256]
    double* ps  = (double*)d_ws;
    double* ps2 = ps  + (size_t)NB * CG * 256;
    double* pdx = ps2 + (size_t)NB * CG * 256;
    float*  pmg = (float*)(pdx + (size_t)NB * CG * 256);

    hg_partial<<<dim3(NB, CG), dim3(256), 0, stream>>>(
        x, mag_w, cn_scale, oct_w, ps, ps2, pdx, pmg);
    hg_wave<<<dim3(KMB, NB), dim3(256), 0, stream>>>(
        ps, ps2, pdx, pmg, mag_b, cn_scale, cn_shift, oct_w, oct_b, out);
}